// Round 12
// baseline (364.267 us; speedup 1.0000x reference)
//
#include <hip/hip_runtime.h>
#include <hip/hip_bf16.h>

#define N_NODES 50000
#define N_EDGES 600000
#define D 128

#define NBUCK 64
#define BUCK_R 782      // ceil(N/64); 64*782 = 50048
#define BCAP 16384      // per-bucket capacity (mean 9375, std 96)
#define EPB 2048        // edges per phaseA block

#define SL_SHIFT 13     // src slice = src >> 13 : 8192 rows/slice, slices 0..6 used
#define NSL 8

typedef __attribute__((ext_vector_type(8))) short bf16x8;
typedef __attribute__((ext_vector_type(4))) float f32x4;
typedef __attribute__((ext_vector_type(2))) float f32x2;

__device__ __forceinline__ const int* pick4(const int* a, const int* b,
                                            const int* c, const int* d, int g) {
    return g == 0 ? a : g == 1 ? b : g == 2 ? c : d;
}
__device__ __forceinline__ const float4* pick4f(const float4* a, const float4* b,
                                                const float4* c, const float4* d, int g) {
    return g == 0 ? a : g == 1 ? b : g == 2 ? c : d;
}

__device__ __forceinline__ unsigned bfpair(float a, float b) {   // RNE pack: lo=a, hi=b
    unsigned ua = __float_as_uint(a); ua = (ua + 0x7FFF + ((ua >> 16) & 1)) >> 16;
    unsigned ub = __float_as_uint(b); ub = (ub + 0x7FFF + ((ub >> 16) & 1)) >> 16;
    return ua | (ub << 16);
}

// ---------- phase A: bucket edges by dst (pairs) and by src (svals) ----------
__global__ __launch_bounds__(256) void phaseA_kernel(
        const int* s0, const int* s1, const int* s2, const int* s3,
        const int* d0, const int* d1, const int* d2, const int* d3,
        int* __restrict__ bCurD, int* __restrict__ bCurS,
        int* __restrict__ pairs, unsigned short* __restrict__ svals, int nEdges) {
    int gi = blockIdx.y;
    const int* src = pick4(s0, s1, s2, s3, gi);
    const int* dst = pick4(d0, d1, d2, d3, gi);
    int* pg = pairs + (size_t)gi * NBUCK * BCAP;
    unsigned short* sg = svals + (size_t)gi * NBUCK * BCAP;

    __shared__ int cntD[64], cntS[64], gposD[64], gposS[64], lcurD[64], lcurS[64];
    int t = threadIdx.x;
    if (t < 64) { cntD[t] = 0; cntS[t] = 0; }
    __syncthreads();

    int myD[8], myS[8];
    int base = blockIdx.x * EPB + t;
    #pragma unroll
    for (int j = 0; j < 8; ++j) {
        int e = base + j * 256;
        if (e < nEdges) {
            myD[j] = dst[e]; myS[j] = src[e];
            atomicAdd(&cntD[myD[j] / BUCK_R], 1);
            atomicAdd(&cntS[myS[j] / BUCK_R], 1);
        } else myD[j] = -1;
    }
    __syncthreads();
    if (t < 64) {
        int c = cntD[t];
        gposD[t] = t * BCAP + (c ? atomicAdd(&bCurD[gi * 64 + t], c) : 0);
        lcurD[t] = 0;
        c = cntS[t];
        gposS[t] = t * BCAP + (c ? atomicAdd(&bCurS[gi * 64 + t], c) : 0);
        lcurS[t] = 0;
    }
    __syncthreads();
    #pragma unroll
    for (int j = 0; j < 8; ++j) {
        if (myD[j] >= 0) {
            int bD = myD[j] / BUCK_R, bS = myS[j] / BUCK_R;
            int lp = atomicAdd(&lcurD[bD], 1);
            pg[gposD[bD] + lp] = ((myD[j] - bD * BUCK_R) << 16) | myS[j];
            int ls = atomicAdd(&lcurS[bS], 1);
            sg[gposS[bS] + ls] = (unsigned short)(myS[j] - bS * BUCK_R);
        }
    }
}

// ---------- csrB: per (graph,bucket): LDS hist + scan + scatter -> rowptr/rsI/eidx ----------
__global__ __launch_bounds__(256) void csrB_kernel(
        const int* __restrict__ bCurD, const int* __restrict__ pairs,
        int* __restrict__ rowptrBase, int* __restrict__ eixBase,
        float* __restrict__ rsIBase) {
    int gi = blockIdx.y, b = blockIdx.x;
    int* rowptr = rowptrBase + (size_t)gi * (N_NODES + 1);
    int* eidx = eixBase + (size_t)gi * N_EDGES;
    float* rsI = rsIBase + (size_t)gi * N_NODES;
    const int* pg = pairs + ((size_t)gi * NBUCK + b) * BCAP;
    const int* bCur = bCurD + gi * 64;

    __shared__ int P[BCAP];
    __shared__ int cnt[1024];
    __shared__ int cur[1024];
    __shared__ int wpart[4];
    __shared__ int sbase;

    int t = threadIdx.x;
    int nb = bCur[b]; if (nb > BCAP) nb = BCAP;

    if (t < 64) {
        int v = (t < b) ? min(bCur[t], BCAP) : 0;
        for (int off = 32; off; off >>= 1) v += __shfl_down(v, off, 64);
        if (t == 0) sbase = v;
    }
    for (int i = t; i < 1024; i += 256) cnt[i] = 0;
    __syncthreads();
    int base = sbase;

    for (int i = t; i < nb; i += 256) {
        int p = pg[i];
        P[i] = p;
        atomicAdd(&cnt[p >> 16], 1);
    }
    __syncthreads();

    int c0 = cnt[t * 4 + 0], c1 = cnt[t * 4 + 1], c2 = cnt[t * 4 + 2], c3 = cnt[t * 4 + 3];
    int ts = c0 + c1 + c2 + c3;
    int lane = t & 63, w = t >> 6;
    int incl = ts;
    for (int off = 1; off < 64; off <<= 1) {
        int u = __shfl_up(incl, off, 64);
        if (lane >= off) incl += u;
    }
    if (lane == 63) wpart[w] = incl;
    __syncthreads();
    int wb = 0;
    #pragma unroll
    for (int i = 0; i < 4; ++i) if (i < w) wb += wpart[i];
    int ex = wb + incl - ts;
    cur[t * 4 + 0] = ex;
    cur[t * 4 + 1] = ex + c0;
    cur[t * 4 + 2] = ex + c0 + c1;
    cur[t * 4 + 3] = ex + c0 + c1 + c2;
    __syncthreads();

    int lo = b * BUCK_R;
    int nh = N_NODES - lo; if (nh > BUCK_R) nh = BUCK_R;
    for (int i = t; i < nh; i += 256) {
        rowptr[lo + i] = base + cur[i];
        rsI[lo + i] = 1.0f / sqrtf(fmaxf((float)cnt[i], 1.0f));
    }
    if (b == NBUCK - 1 && t == 0) rowptr[N_NODES] = N_EDGES;
    __syncthreads();

    for (int i = t; i < nb; i += 256) {
        int p = P[i];
        int pos = atomicAdd(&cur[p >> 16], 1);
        eidx[base + pos] = p & 0xFFFF;   // src
    }
}

// ---------- csrC: per (graph,bucket): LDS hist of src -> rsO ----------
__global__ __launch_bounds__(256) void csrC_kernel(
        const int* __restrict__ bCurS, const unsigned short* __restrict__ svals,
        float* __restrict__ rsOBase) {
    int gi = blockIdx.y, b = blockIdx.x;
    float* rsO = rsOBase + (size_t)gi * N_NODES;
    const unsigned short* sg = svals + ((size_t)gi * NBUCK + b) * BCAP;
    __shared__ int cnt[1024];
    int t = threadIdx.x;
    for (int i = t; i < 1024; i += 256) cnt[i] = 0;
    __syncthreads();
    int ns = bCurS[gi * 64 + b]; if (ns > BCAP) ns = BCAP;
    for (int i = t; i < ns; i += 256) atomicAdd(&cnt[sg[i]], 1);
    __syncthreads();
    int lo = b * BUCK_R;
    int nh = N_NODES - lo; if (nh > BUCK_R) nh = BUCK_R;
    for (int i = t; i < nh; i += 256)
        rsO[lo + i] = 1.0f / sqrtf(fmaxf((float)cnt[i], 1.0f));
}

// ---------- rowsort: per row, counting-sort edge list by src slice (src>>13) ----------
// Register-only: byte-packed counters in a ulong + byte-parallel prefix sum.
// Emits rp8[r][8] slice start offsets and slice-ordered eidx2.
__global__ __launch_bounds__(256) void rowsort_kernel(
        const int* __restrict__ rowptrBase, const int* __restrict__ eixBase,
        int* __restrict__ rp8Base, int* __restrict__ eix2Base) {
    int gi = blockIdx.y;
    int r = blockIdx.x * 256 + threadIdx.x;
    if (r >= N_NODES) return;
    const int* rowptr = rowptrBase + (size_t)gi * (N_NODES + 1);
    const int* eidx   = eixBase + (size_t)gi * N_EDGES;
    int* rp8   = rp8Base + (size_t)gi * N_NODES * NSL;
    int* eidx2 = eix2Base + (size_t)gi * N_EDGES;

    int beg = rowptr[r], end = rowptr[r + 1];
    unsigned long long cnt = 0ULL;
    for (int p = beg; p < end; ++p)
        cnt += 1ULL << ((unsigned)(eidx[p] >> SL_SHIFT) * 8);
    // byte-parallel inclusive prefix, then shift for exclusive
    unsigned long long incl = cnt;
    incl += incl << 8; incl += incl << 16; incl += incl << 32;
    unsigned long long excl = incl << 8;
    #pragma unroll
    for (int s = 0; s < NSL; ++s)
        rp8[(size_t)r * NSL + s] = beg + (int)((excl >> (s * 8)) & 0xFF);
    unsigned long long cur = excl;
    for (int p = beg; p < end; ++p) {
        int v = eidx[p];
        unsigned s8 = (unsigned)(v >> SL_SHIFT) * 8;
        eidx2[beg + (int)((cur >> s8) & 0xFF)] = v;
        cur += 1ULL << s8;
    }
}

// ---------- W fp32 -> packed bf16 MFMA B-fragment layout ----------
__global__ void wconv_kernel(const float* __restrict__ W1, const float* __restrict__ W2,
                             unsigned* __restrict__ Wp1, unsigned* __restrict__ Wp2) {
    const float* W = blockIdx.y ? W2 : W1;
    unsigned* Wp = blockIdx.y ? Wp2 : Wp1;
    int o = blockIdx.x * 256 + threadIdx.x;      // 0..8191
    int j2 = o & 3, lane = (o >> 2) & 63, nt = (o >> 8) & 7, kc = o >> 11;
    int k = kc * 32 + (lane >> 4) * 8 + j2 * 2;
    int col = nt * 16 + (lane & 15);
    Wp[o] = bfpair(W[k * 128 + col], W[(k + 1) * 128 + col]);
}

// ---------- x -> fp8 e4m3 with rsO pre-scale, row-major [N][128] ----------
__global__ void xconv_kernel(const float4* x0, const float4* x1,
                             const float4* x2, const float4* x3,
                             const float* __restrict__ rsOBase,
                             uint2* __restrict__ xbBase, int gFirst, int n /* N*16 */) {
    int gi = blockIdx.y;
    const float4* x = pick4f(x0, x1, x2, x3, gFirst + gi);
    const float* rsO = rsOBase + (size_t)(gFirst + gi) * N_NODES;
    uint2* xb = xbBase + (size_t)gi * (N_NODES * 16);   // 16 uint2 per 128-fp8 row
    int i = blockIdx.x * blockDim.x + threadIdx.x;
    if (i >= n) return;
    float sc = rsO[i >> 4];
    float4 a = x[i * 2];
    float4 b = x[i * 2 + 1];
    int w0 = __builtin_amdgcn_cvt_pk_fp8_f32(a.x * sc, a.y * sc, 0, false);
    w0 = __builtin_amdgcn_cvt_pk_fp8_f32(a.z * sc, a.w * sc, w0, true);
    int w1 = __builtin_amdgcn_cvt_pk_fp8_f32(b.x * sc, b.y * sc, 0, false);
    w1 = __builtin_amdgcn_cvt_pk_fp8_f32(b.z * sc, b.w * sc, w1, true);
    xb[i] = make_uint2((unsigned)w0, (unsigned)w1);
}

// ---------- fused gather (fp8, src-slice-phased) + MFMA GEMM (bf16 W) ----------
// 32-row chunk per block: 8 thr/row gather h[eidx2[p]] via uint4 (16 fp8), edges
// walked slice-by-slice (rp8) so the active table window is ~4 MB (L2-resident);
// f32 accum persists across slices; rsI-scale; bf16 -> LDS A[32][136]; 4 waves do
// 2 row-tiles x 2 col-tiles of 16x16x32 MFMA.
// LAYER 1: out fp8 = fp8(relu(.+b)*rsO);  LAYER 2: acc += sum(relu(.+b))
#define NCH32 1563   // ceil(50000/32)

#define ACC16(U)                                                            \
    {                                                                       \
        f32x2 e0 = __builtin_amdgcn_cvt_pk_f32_fp8((U).x, false);           \
        f32x2 e1 = __builtin_amdgcn_cvt_pk_f32_fp8((U).x, true);            \
        f32x2 e2 = __builtin_amdgcn_cvt_pk_f32_fp8((U).y, false);           \
        f32x2 e3 = __builtin_amdgcn_cvt_pk_f32_fp8((U).y, true);            \
        f32x2 e4 = __builtin_amdgcn_cvt_pk_f32_fp8((U).z, false);           \
        f32x2 e5 = __builtin_amdgcn_cvt_pk_f32_fp8((U).z, true);            \
        f32x2 e6 = __builtin_amdgcn_cvt_pk_f32_fp8((U).w, false);           \
        f32x2 e7 = __builtin_amdgcn_cvt_pk_f32_fp8((U).w, true);            \
        a[0] += e0[0];  a[1] += e0[1];  a[2] += e1[0];  a[3] += e1[1];      \
        a[4] += e2[0];  a[5] += e2[1];  a[6] += e3[0];  a[7] += e3[1];      \
        a[8] += e4[0];  a[9] += e4[1];  a[10] += e5[0]; a[11] += e5[1];     \
        a[12] += e6[0]; a[13] += e6[1]; a[14] += e7[0]; a[15] += e7[1];     \
    }

template <int LAYER>
__global__ __launch_bounds__(256) void fused_kernel(
        const int* __restrict__ rowptrBase, const int* __restrict__ rp8Base,
        const int* __restrict__ eix2Base,
        const unsigned char* __restrict__ hBase,     // [gli][N][128] fp8
        const float* __restrict__ rsIBase, const float* __restrict__ rsOBase,
        const uint4* __restrict__ Wp, const float* __restrict__ bias,
        unsigned char* __restrict__ outBase, double* __restrict__ acc, int gFirst) {
    const int gi = blockIdx.y;
    const int g = gFirst + gi;
    const int* rowptr = rowptrBase + (size_t)g * (N_NODES + 1);
    const int* rp8    = rp8Base + (size_t)g * N_NODES * NSL;
    const int* eidx   = eix2Base + (size_t)g * N_EDGES;
    const float* rsI  = rsIBase + (size_t)g * N_NODES;
    const float* rsO  = rsOBase + (size_t)g * N_NODES;
    const unsigned char* h = hBase + (size_t)gi * N_NODES * D;
    unsigned char* outb = outBase + (size_t)gi * N_NODES * D;

    __shared__ unsigned short A[32][136];    // bf16 staging, padded stride

    const int t = threadIdx.x;
    const int row = t >> 3;          // 0..31
    const int sub = t & 7;           // 16-col (16 B) slice
    const int lane = t & 63, wv = t >> 6;
    const int l15 = lane & 15, lh = lane >> 4;

    // W fragments: register-resident
    bf16x8 bfr[4][2];
    #pragma unroll
    for (int kc = 0; kc < 4; ++kc)
        #pragma unroll
        for (int j = 0; j < 2; ++j) {
            uint4 u = Wp[(kc * 8 + wv * 2 + j) * 64 + lane];
            bfr[kc][j] = *(bf16x8*)&u;
        }
    float bv[2];
    #pragma unroll
    for (int j = 0; j < 2; ++j) bv[j] = bias[wv * 32 + j * 16 + l15];

    const int ch = blockIdx.x;
    const int r = ch * 32 + row;
    float sc = 0.f;
    int rp[NSL + 1];
    if (r < N_NODES) {
        #pragma unroll
        for (int s = 0; s < NSL; ++s) rp[s] = rp8[(size_t)r * NSL + s];
        rp[NSL] = rowptr[r + 1];
        sc = rsI[r];
    } else {
        #pragma unroll
        for (int s = 0; s <= NSL; ++s) rp[s] = 0;
    }

    // ---- gather phase: slice-ordered, accum persists across slices ----
    float a[16];
    #pragma unroll
    for (int j = 0; j < 16; ++j) a[j] = 0.f;
    const unsigned char* hp = h + sub * 16;
    #pragma unroll
    for (int s = 0; s < NSL; ++s) {
        int p = rp[s], pe = rp[s + 1];
        for (; p + 2 <= pe; p += 2) {
            uint4 u0 = *(const uint4*)(hp + (size_t)eidx[p] * 128);
            uint4 u1 = *(const uint4*)(hp + (size_t)eidx[p + 1] * 128);
            ACC16(u0) ACC16(u1)
        }
        if (p < pe) {
            uint4 u0 = *(const uint4*)(hp + (size_t)eidx[p] * 128);
            ACC16(u0)
        }
    }
    {
        uint4 pkA, pkB;
        pkA.x = bfpair(a[0] * sc, a[1] * sc);
        pkA.y = bfpair(a[2] * sc, a[3] * sc);
        pkA.z = bfpair(a[4] * sc, a[5] * sc);
        pkA.w = bfpair(a[6] * sc, a[7] * sc);
        pkB.x = bfpair(a[8] * sc, a[9] * sc);
        pkB.y = bfpair(a[10] * sc, a[11] * sc);
        pkB.z = bfpair(a[12] * sc, a[13] * sc);
        pkB.w = bfpair(a[14] * sc, a[15] * sc);
        *(uint4*)&A[row][sub * 16]     = pkA;
        *(uint4*)&A[row][sub * 16 + 8] = pkB;
    }
    __syncthreads();

    // ---- MFMA phase: 2 row-tiles x 2 col-tiles ----
    f32x4 c[2][2];
    #pragma unroll
    for (int ti = 0; ti < 2; ++ti) {
        c[ti][0] = (f32x4){0.f, 0.f, 0.f, 0.f};
        c[ti][1] = (f32x4){0.f, 0.f, 0.f, 0.f};
    }
    #pragma unroll
    for (int ti = 0; ti < 2; ++ti) {
        #pragma unroll
        for (int kc = 0; kc < 4; ++kc) {
            uint4 u = *(const uint4*)&A[ti * 16 + l15][kc * 32 + lh * 8];
            bf16x8 afr = *(bf16x8*)&u;
            c[ti][0] = __builtin_amdgcn_mfma_f32_16x16x32_bf16(afr, bfr[kc][0], c[ti][0], 0, 0, 0);
            c[ti][1] = __builtin_amdgcn_mfma_f32_16x16x32_bf16(afr, bfr[kc][1], c[ti][1], 0, 0, 0);
        }
    }

    // ---- epilogue ----
    double lsum = 0.0;
    #pragma unroll
    for (int ti = 0; ti < 2; ++ti) {
        const int r0 = ch * 32 + ti * 16 + lh * 4;
        #pragma unroll
        for (int jj = 0; jj < 4; ++jj) {
            int rr = r0 + jj;
            if (rr < N_NODES) {
                float o0 = fmaxf(c[ti][0][jj] + bv[0], 0.f);
                float o1 = fmaxf(c[ti][1][jj] + bv[1], 0.f);
                if (LAYER == 2) {
                    lsum += (double)o0 + (double)o1;
                } else {
                    float s2 = rsO[rr];
                    float q0 = o0 * s2, q1 = o1 * s2;
                    unsigned b0 = (unsigned)__builtin_amdgcn_cvt_pk_fp8_f32(q0, q0, 0, false);
                    unsigned b1 = (unsigned)__builtin_amdgcn_cvt_pk_fp8_f32(q1, q1, 0, false);
                    outb[(size_t)rr * 128 + wv * 32 + l15]      = (unsigned char)(b0 & 0xFF);
                    outb[(size_t)rr * 128 + wv * 32 + 16 + l15] = (unsigned char)(b1 & 0xFF);
                }
            }
        }
    }

    if (LAYER == 2) {
        for (int off = 32; off; off >>= 1) lsum += __shfl_down(lsum, off, 64);
        __shared__ double wred[4];
        if (lane == 0) wred[wv] = lsum;
        __syncthreads();
        if (t == 0) atomicAdd(acc, wred[0] + wred[1] + wred[2] + wred[3]);
    }
}

__global__ void finalize_kernel(const double* __restrict__ acc, float* __restrict__ out) {
    if (threadIdx.x == 0 && blockIdx.x == 0)
        out[0] = (float)(acc[0] / (4.0 * N_NODES * D));
}

extern "C" void kernel_launch(void* const* d_in, const int* in_sizes, int n_in,
                              void* d_out, int out_size, void* d_ws, size_t ws_size,
                              hipStream_t stream) {
    const float* x[4];
    const int* src[4];
    const int* dst[4];
    for (int g = 0; g < 4; ++g) {
        x[g]   = (const float*)d_in[3 * g + 0];
        src[g] = (const int*)  d_in[3 * g + 1];
        dst[g] = (const int*)  d_in[3 * g + 2];
    }
    const float* W1 = (const float*)d_in[12];
    const float* b1 = (const float*)d_in[13];
    const float* W2 = (const float*)d_in[14];
    const float* b2 = (const float*)d_in[15];
    float* out = (float*)d_out;

    // -------- workspace layout (4-byte units) --------
    int* ws32 = (int*)d_ws;
    double* acc     = (double*)d_ws;
    int* bCurD      = ws32 + 64;
    int* bCurS      = ws32 + 320;
    unsigned* Wp1   = (unsigned*)(ws32 + 1024);
    unsigned* Wp2   = Wp1 + 8192;
    int* rowptrBase = ws32 + 17408;
    float* rsIBase  = (float*)(ws32 + 217412);
    float* rsOBase  = (float*)(ws32 + 417412);
    int* eixBase    = ws32 + 617412;
    int* pairs      = ws32 + 3017412;
    unsigned short* svals = (unsigned short*)(pairs + 4194304);
    unsigned char* xbA    = (unsigned char*)(ws32 + 3017412);

    auto overlayUnits = [](int gb) -> size_t {
        size_t ov = (size_t)gb * 3200000;   // xb + Ab per graph (fp8), 4B units
        if (ov < 6291456) ov = 6291456;     // at least pairs+svals overlay
        return ov;
    };
    auto needBytes = [&](int gb) -> size_t {
        // overlay + rp8[4][N][8] (1600000) + eidx2[4][E] (2400000)
        return (3017412 + overlayUnits(gb) + 1600000 + 2400000) * 4 + 4096;
    };
    int gb = 1;
    if (ws_size >= needBytes(4)) gb = 4;
    else if (ws_size >= needBytes(2)) gb = 2;
    unsigned char* AbA = xbA + (size_t)gb * N_NODES * D;
    int* rp8Base  = ws32 + 3017412 + overlayUnits(gb);
    int* eix2Base = rp8Base + 1600000;

    const int paGrid    = (N_EDGES + EPB - 1) / EPB;       // 293
    const int xconvGrid = (N_NODES * 16 + 255) / 256;      // 3125
    const int sortGrid  = (N_NODES + 255) / 256;           // 196

    hipMemsetAsync(d_ws, 0, 1024 * sizeof(int), stream);

    wconv_kernel<<<dim3(32, 2), 256, 0, stream>>>(W1, W2, Wp1, Wp2);
    phaseA_kernel<<<dim3(paGrid, 4), 256, 0, stream>>>(
        src[0], src[1], src[2], src[3], dst[0], dst[1], dst[2], dst[3],
        bCurD, bCurS, pairs, svals, N_EDGES);
    csrB_kernel<<<dim3(NBUCK, 4), 256, 0, stream>>>(
        bCurD, pairs, rowptrBase, eixBase, rsIBase);
    csrC_kernel<<<dim3(NBUCK, 4), 256, 0, stream>>>(bCurS, svals, rsOBase);
    rowsort_kernel<<<dim3(sortGrid, 4), 256, 0, stream>>>(
        rowptrBase, eixBase, rp8Base, eix2Base);

    for (int g0 = 0; g0 < 4; g0 += gb) {
        int nb = 4 - g0 < gb ? 4 - g0 : gb;
        xconv_kernel<<<dim3(xconvGrid, nb), 256, 0, stream>>>(
            (const float4*)x[0], (const float4*)x[1], (const float4*)x[2], (const float4*)x[3],
            rsOBase, (uint2*)xbA, g0, N_NODES * 16);
        fused_kernel<1><<<dim3(NCH32, nb), 256, 0, stream>>>(
            rowptrBase, rp8Base, eix2Base, xbA, rsIBase, rsOBase,
            (const uint4*)Wp1, b1, AbA, nullptr, g0);
        fused_kernel<2><<<dim3(NCH32, nb), 256, 0, stream>>>(
            rowptrBase, rp8Base, eix2Base, AbA, rsIBase, rsOBase,
            (const uint4*)Wp2, b2, nullptr, acc, g0);
    }

    finalize_kernel<<<1, 64, 0, stream>>>(acc, out);
}

// Round 13
// 306.447 us; speedup vs baseline: 1.1887x; 1.1887x over previous
//
#include <hip/hip_runtime.h>
#include <hip/hip_bf16.h>

#define N_NODES 50000
#define N_EDGES 600000
#define D 128

#define NBUCK 64
#define BUCK_R 782      // ceil(N/64); 64*782 = 50048
#define BCAP 16384      // per-bucket capacity (mean 9375, std 96)
#define EPB 2048        // edges per phaseA block

typedef __attribute__((ext_vector_type(8))) short bf16x8;
typedef __attribute__((ext_vector_type(4))) float f32x4;
typedef __attribute__((ext_vector_type(2))) float f32x2;

__device__ __forceinline__ const int* pick4(const int* a, const int* b,
                                            const int* c, const int* d, int g) {
    return g == 0 ? a : g == 1 ? b : g == 2 ? c : d;
}
__device__ __forceinline__ const float4* pick4f(const float4* a, const float4* b,
                                                const float4* c, const float4* d, int g) {
    return g == 0 ? a : g == 1 ? b : g == 2 ? c : d;
}

__device__ __forceinline__ unsigned bfpair(float a, float b) {   // RNE pack: lo=a, hi=b
    unsigned ua = __float_as_uint(a); ua = (ua + 0x7FFF + ((ua >> 16) & 1)) >> 16;
    unsigned ub = __float_as_uint(b); ub = (ub + 0x7FFF + ((ub >> 16) & 1)) >> 16;
    return ua | (ub << 16);
}

// ---------- phase A: bucket edges by dst (pairs) and by src (svals) ----------
__global__ __launch_bounds__(256) void phaseA_kernel(
        const int* s0, const int* s1, const int* s2, const int* s3,
        const int* d0, const int* d1, const int* d2, const int* d3,
        int* __restrict__ bCurD, int* __restrict__ bCurS,
        int* __restrict__ pairs, unsigned short* __restrict__ svals, int nEdges) {
    int gi = blockIdx.y;
    const int* src = pick4(s0, s1, s2, s3, gi);
    const int* dst = pick4(d0, d1, d2, d3, gi);
    int* pg = pairs + (size_t)gi * NBUCK * BCAP;
    unsigned short* sg = svals + (size_t)gi * NBUCK * BCAP;

    __shared__ int cntD[64], cntS[64], gposD[64], gposS[64], lcurD[64], lcurS[64];
    int t = threadIdx.x;
    if (t < 64) { cntD[t] = 0; cntS[t] = 0; }
    __syncthreads();

    int myD[8], myS[8];
    int base = blockIdx.x * EPB + t;
    #pragma unroll
    for (int j = 0; j < 8; ++j) {
        int e = base + j * 256;
        if (e < nEdges) {
            myD[j] = dst[e]; myS[j] = src[e];
            atomicAdd(&cntD[myD[j] / BUCK_R], 1);
            atomicAdd(&cntS[myS[j] / BUCK_R], 1);
        } else myD[j] = -1;
    }
    __syncthreads();
    if (t < 64) {
        int c = cntD[t];
        gposD[t] = t * BCAP + (c ? atomicAdd(&bCurD[gi * 64 + t], c) : 0);
        lcurD[t] = 0;
        c = cntS[t];
        gposS[t] = t * BCAP + (c ? atomicAdd(&bCurS[gi * 64 + t], c) : 0);
        lcurS[t] = 0;
    }
    __syncthreads();
    #pragma unroll
    for (int j = 0; j < 8; ++j) {
        if (myD[j] >= 0) {
            int bD = myD[j] / BUCK_R, bS = myS[j] / BUCK_R;
            int lp = atomicAdd(&lcurD[bD], 1);
            pg[gposD[bD] + lp] = ((myD[j] - bD * BUCK_R) << 16) | myS[j];
            int ls = atomicAdd(&lcurS[bS], 1);
            sg[gposS[bS] + ls] = (unsigned short)(myS[j] - bS * BUCK_R);
        }
    }
}

// ---------- csrB: per (graph,bucket): LDS hist + scan + scatter -> rowptr/rsI/eidx ----------
__global__ __launch_bounds__(256) void csrB_kernel(
        const int* __restrict__ bCurD, const int* __restrict__ pairs,
        int* __restrict__ rowptrBase, int* __restrict__ eixBase,
        float* __restrict__ rsIBase) {
    int gi = blockIdx.y, b = blockIdx.x;
    int* rowptr = rowptrBase + (size_t)gi * (N_NODES + 1);
    int* eidx = eixBase + (size_t)gi * N_EDGES;
    float* rsI = rsIBase + (size_t)gi * N_NODES;
    const int* pg = pairs + ((size_t)gi * NBUCK + b) * BCAP;
    const int* bCur = bCurD + gi * 64;

    __shared__ int P[BCAP];
    __shared__ int cnt[1024];
    __shared__ int cur[1024];
    __shared__ int wpart[4];
    __shared__ int sbase;

    int t = threadIdx.x;
    int nb = bCur[b]; if (nb > BCAP) nb = BCAP;

    if (t < 64) {
        int v = (t < b) ? min(bCur[t], BCAP) : 0;
        for (int off = 32; off; off >>= 1) v += __shfl_down(v, off, 64);
        if (t == 0) sbase = v;
    }
    for (int i = t; i < 1024; i += 256) cnt[i] = 0;
    __syncthreads();
    int base = sbase;

    for (int i = t; i < nb; i += 256) {
        int p = pg[i];
        P[i] = p;
        atomicAdd(&cnt[p >> 16], 1);
    }
    __syncthreads();

    int c0 = cnt[t * 4 + 0], c1 = cnt[t * 4 + 1], c2 = cnt[t * 4 + 2], c3 = cnt[t * 4 + 3];
    int ts = c0 + c1 + c2 + c3;
    int lane = t & 63, w = t >> 6;
    int incl = ts;
    for (int off = 1; off < 64; off <<= 1) {
        int u = __shfl_up(incl, off, 64);
        if (lane >= off) incl += u;
    }
    if (lane == 63) wpart[w] = incl;
    __syncthreads();
    int wb = 0;
    #pragma unroll
    for (int i = 0; i < 4; ++i) if (i < w) wb += wpart[i];
    int ex = wb + incl - ts;
    cur[t * 4 + 0] = ex;
    cur[t * 4 + 1] = ex + c0;
    cur[t * 4 + 2] = ex + c0 + c1;
    cur[t * 4 + 3] = ex + c0 + c1 + c2;
    __syncthreads();

    int lo = b * BUCK_R;
    int nh = N_NODES - lo; if (nh > BUCK_R) nh = BUCK_R;
    for (int i = t; i < nh; i += 256) {
        rowptr[lo + i] = base + cur[i];
        rsI[lo + i] = 1.0f / sqrtf(fmaxf((float)cnt[i], 1.0f));
    }
    if (b == NBUCK - 1 && t == 0) rowptr[N_NODES] = N_EDGES;
    __syncthreads();

    for (int i = t; i < nb; i += 256) {
        int p = P[i];
        int pos = atomicAdd(&cur[p >> 16], 1);
        eidx[base + pos] = p & 0xFFFF;   // src
    }
}

// ---------- csrC: per (graph,bucket): LDS hist of src -> rsO ----------
__global__ __launch_bounds__(256) void csrC_kernel(
        const int* __restrict__ bCurS, const unsigned short* __restrict__ svals,
        float* __restrict__ rsOBase) {
    int gi = blockIdx.y, b = blockIdx.x;
    float* rsO = rsOBase + (size_t)gi * N_NODES;
    const unsigned short* sg = svals + ((size_t)gi * NBUCK + b) * BCAP;
    __shared__ int cnt[1024];
    int t = threadIdx.x;
    for (int i = t; i < 1024; i += 256) cnt[i] = 0;
    __syncthreads();
    int ns = bCurS[gi * 64 + b]; if (ns > BCAP) ns = BCAP;
    for (int i = t; i < ns; i += 256) atomicAdd(&cnt[sg[i]], 1);
    __syncthreads();
    int lo = b * BUCK_R;
    int nh = N_NODES - lo; if (nh > BUCK_R) nh = BUCK_R;
    for (int i = t; i < nh; i += 256)
        rsO[lo + i] = 1.0f / sqrtf(fmaxf((float)cnt[i], 1.0f));
}

// ---------- W fp32 -> packed bf16 MFMA B-fragment layout ----------
__global__ void wconv_kernel(const float* __restrict__ W1, const float* __restrict__ W2,
                             unsigned* __restrict__ Wp1, unsigned* __restrict__ Wp2) {
    const float* W = blockIdx.y ? W2 : W1;
    unsigned* Wp = blockIdx.y ? Wp2 : Wp1;
    int o = blockIdx.x * 256 + threadIdx.x;      // 0..8191
    int j2 = o & 3, lane = (o >> 2) & 63, nt = (o >> 8) & 7, kc = o >> 11;
    int k = kc * 32 + (lane >> 4) * 8 + j2 * 2;
    int col = nt * 16 + (lane & 15);
    Wp[o] = bfpair(W[k * 128 + col], W[(k + 1) * 128 + col]);
}

// ---------- x -> fp8 e4m3 with rsO pre-scale, row-major [N][128] ----------
__global__ void xconv_kernel(const float4* x0, const float4* x1,
                             const float4* x2, const float4* x3,
                             const float* __restrict__ rsOBase,
                             uint2* __restrict__ xbBase, int gFirst, int n /* N*16 */) {
    int gi = blockIdx.y;
    const float4* x = pick4f(x0, x1, x2, x3, gFirst + gi);
    const float* rsO = rsOBase + (size_t)(gFirst + gi) * N_NODES;
    uint2* xb = xbBase + (size_t)gi * (N_NODES * 16);   // 16 uint2 per 128-fp8 row
    int i = blockIdx.x * blockDim.x + threadIdx.x;
    if (i >= n) return;
    float sc = rsO[i >> 4];
    float4 a = x[i * 2];
    float4 b = x[i * 2 + 1];
    int w0 = __builtin_amdgcn_cvt_pk_fp8_f32(a.x * sc, a.y * sc, 0, false);
    w0 = __builtin_amdgcn_cvt_pk_fp8_f32(a.z * sc, a.w * sc, w0, true);
    int w1 = __builtin_amdgcn_cvt_pk_fp8_f32(b.x * sc, b.y * sc, 0, false);
    w1 = __builtin_amdgcn_cvt_pk_fp8_f32(b.z * sc, b.w * sc, w1, true);
    xb[i] = make_uint2((unsigned)w0, (unsigned)w1);
}

// ---------- fused gather (fp8, 16B loads, unroll-4) + MFMA GEMM (bf16 W) ----------
// 32-row chunk per block: 8 thr/row gather h[eidx[p]] via uint4 (16 fp8), 4 edges
// in flight; f32 accum; rsI-scale; bf16 -> LDS A[32][136]; 4 waves do 2 row-tiles
// x 2 col-tiles of 16x16x32 MFMA.
// LAYER 1: out fp8 = fp8(relu(.+b)*rsO);  LAYER 2: acc += sum(relu(.+b))
#define NCH32 1563   // ceil(50000/32)

#define ACC16(U)                                                            \
    {                                                                       \
        f32x2 e0 = __builtin_amdgcn_cvt_pk_f32_fp8((U).x, false);           \
        f32x2 e1 = __builtin_amdgcn_cvt_pk_f32_fp8((U).x, true);            \
        f32x2 e2 = __builtin_amdgcn_cvt_pk_f32_fp8((U).y, false);           \
        f32x2 e3 = __builtin_amdgcn_cvt_pk_f32_fp8((U).y, true);            \
        f32x2 e4 = __builtin_amdgcn_cvt_pk_f32_fp8((U).z, false);           \
        f32x2 e5 = __builtin_amdgcn_cvt_pk_f32_fp8((U).z, true);            \
        f32x2 e6 = __builtin_amdgcn_cvt_pk_f32_fp8((U).w, false);           \
        f32x2 e7 = __builtin_amdgcn_cvt_pk_f32_fp8((U).w, true);            \
        a[0] += e0[0];  a[1] += e0[1];  a[2] += e1[0];  a[3] += e1[1];      \
        a[4] += e2[0];  a[5] += e2[1];  a[6] += e3[0];  a[7] += e3[1];      \
        a[8] += e4[0];  a[9] += e4[1];  a[10] += e5[0]; a[11] += e5[1];     \
        a[12] += e6[0]; a[13] += e6[1]; a[14] += e7[0]; a[15] += e7[1];     \
    }

template <int LAYER>
__global__ __launch_bounds__(256) void fused_kernel(
        const int* __restrict__ rowptrBase, const int* __restrict__ eixBase,
        const unsigned char* __restrict__ hBase,     // [gli][N][128] fp8
        const float* __restrict__ rsIBase, const float* __restrict__ rsOBase,
        const uint4* __restrict__ Wp, const float* __restrict__ bias,
        unsigned char* __restrict__ outBase, double* __restrict__ acc, int gFirst) {
    const int gi = blockIdx.y;
    const int g = gFirst + gi;
    const int* rowptr = rowptrBase + (size_t)g * (N_NODES + 1);
    const int* eidx   = eixBase + (size_t)g * N_EDGES;
    const float* rsI  = rsIBase + (size_t)g * N_NODES;
    const float* rsO  = rsOBase + (size_t)g * N_NODES;
    const unsigned char* h = hBase + (size_t)gi * N_NODES * D;
    unsigned char* outb = outBase + (size_t)gi * N_NODES * D;

    __shared__ unsigned short A[32][136];    // bf16 staging, padded stride

    const int t = threadIdx.x;
    const int row = t >> 3;          // 0..31
    const int sub = t & 7;           // 16-col (16 B) slice
    const int lane = t & 63, wv = t >> 6;
    const int l15 = lane & 15, lh = lane >> 4;

    // W fragments: register-resident
    bf16x8 bfr[4][2];
    #pragma unroll
    for (int kc = 0; kc < 4; ++kc)
        #pragma unroll
        for (int j = 0; j < 2; ++j) {
            uint4 u = Wp[(kc * 8 + wv * 2 + j) * 64 + lane];
            bfr[kc][j] = *(bf16x8*)&u;
        }
    float bv[2];
    #pragma unroll
    for (int j = 0; j < 2; ++j) bv[j] = bias[wv * 32 + j * 16 + l15];

    const int ch = blockIdx.x;
    const int r = ch * 32 + row;
    int p = 0, pend = 0;
    float sc = 0.f;
    if (r < N_NODES) { p = rowptr[r]; pend = rowptr[r + 1]; sc = rsI[r]; }

    // ---- gather phase: 16 B/edge/thread, 4 edges in flight ----
    float a[16];
    #pragma unroll
    for (int j = 0; j < 16; ++j) a[j] = 0.f;
    const unsigned char* hp = h + sub * 16;
    for (; p + 4 <= pend; p += 4) {
        uint4 u0 = *(const uint4*)(hp + (size_t)eidx[p] * 128);
        uint4 u1 = *(const uint4*)(hp + (size_t)eidx[p + 1] * 128);
        uint4 u2 = *(const uint4*)(hp + (size_t)eidx[p + 2] * 128);
        uint4 u3 = *(const uint4*)(hp + (size_t)eidx[p + 3] * 128);
        ACC16(u0) ACC16(u1) ACC16(u2) ACC16(u3)
    }
    for (; p < pend; ++p) {
        uint4 u0 = *(const uint4*)(hp + (size_t)eidx[p] * 128);
        ACC16(u0)
    }
    {
        uint4 pkA, pkB;
        pkA.x = bfpair(a[0] * sc, a[1] * sc);
        pkA.y = bfpair(a[2] * sc, a[3] * sc);
        pkA.z = bfpair(a[4] * sc, a[5] * sc);
        pkA.w = bfpair(a[6] * sc, a[7] * sc);
        pkB.x = bfpair(a[8] * sc, a[9] * sc);
        pkB.y = bfpair(a[10] * sc, a[11] * sc);
        pkB.z = bfpair(a[12] * sc, a[13] * sc);
        pkB.w = bfpair(a[14] * sc, a[15] * sc);
        *(uint4*)&A[row][sub * 16]     = pkA;
        *(uint4*)&A[row][sub * 16 + 8] = pkB;
    }
    __syncthreads();

    // ---- MFMA phase: 2 row-tiles x 2 col-tiles ----
    f32x4 c[2][2];
    #pragma unroll
    for (int ti = 0; ti < 2; ++ti) {
        c[ti][0] = (f32x4){0.f, 0.f, 0.f, 0.f};
        c[ti][1] = (f32x4){0.f, 0.f, 0.f, 0.f};
    }
    #pragma unroll
    for (int ti = 0; ti < 2; ++ti) {
        #pragma unroll
        for (int kc = 0; kc < 4; ++kc) {
            uint4 u = *(const uint4*)&A[ti * 16 + l15][kc * 32 + lh * 8];
            bf16x8 afr = *(bf16x8*)&u;
            c[ti][0] = __builtin_amdgcn_mfma_f32_16x16x32_bf16(afr, bfr[kc][0], c[ti][0], 0, 0, 0);
            c[ti][1] = __builtin_amdgcn_mfma_f32_16x16x32_bf16(afr, bfr[kc][1], c[ti][1], 0, 0, 0);
        }
    }

    // ---- epilogue ----
    double lsum = 0.0;
    #pragma unroll
    for (int ti = 0; ti < 2; ++ti) {
        const int r0 = ch * 32 + ti * 16 + lh * 4;
        #pragma unroll
        for (int jj = 0; jj < 4; ++jj) {
            int rr = r0 + jj;
            if (rr < N_NODES) {
                float o0 = fmaxf(c[ti][0][jj] + bv[0], 0.f);
                float o1 = fmaxf(c[ti][1][jj] + bv[1], 0.f);
                if (LAYER == 2) {
                    lsum += (double)o0 + (double)o1;
                } else {
                    float s2 = rsO[rr];
                    float q0 = o0 * s2, q1 = o1 * s2;
                    unsigned b0 = (unsigned)__builtin_amdgcn_cvt_pk_fp8_f32(q0, q0, 0, false);
                    unsigned b1 = (unsigned)__builtin_amdgcn_cvt_pk_fp8_f32(q1, q1, 0, false);
                    outb[(size_t)rr * 128 + wv * 32 + l15]      = (unsigned char)(b0 & 0xFF);
                    outb[(size_t)rr * 128 + wv * 32 + 16 + l15] = (unsigned char)(b1 & 0xFF);
                }
            }
        }
    }

    if (LAYER == 2) {
        for (int off = 32; off; off >>= 1) lsum += __shfl_down(lsum, off, 64);
        __shared__ double wred[4];
        if (lane == 0) wred[wv] = lsum;
        __syncthreads();
        if (t == 0) atomicAdd(acc, wred[0] + wred[1] + wred[2] + wred[3]);
    }
}

__global__ void finalize_kernel(const double* __restrict__ acc, float* __restrict__ out) {
    if (threadIdx.x == 0 && blockIdx.x == 0)
        out[0] = (float)(acc[0] / (4.0 * N_NODES * D));
}

extern "C" void kernel_launch(void* const* d_in, const int* in_sizes, int n_in,
                              void* d_out, int out_size, void* d_ws, size_t ws_size,
                              hipStream_t stream) {
    const float* x[4];
    const int* src[4];
    const int* dst[4];
    for (int g = 0; g < 4; ++g) {
        x[g]   = (const float*)d_in[3 * g + 0];
        src[g] = (const int*)  d_in[3 * g + 1];
        dst[g] = (const int*)  d_in[3 * g + 2];
    }
    const float* W1 = (const float*)d_in[12];
    const float* b1 = (const float*)d_in[13];
    const float* W2 = (const float*)d_in[14];
    const float* b2 = (const float*)d_in[15];
    float* out = (float*)d_out;

    // -------- workspace layout (4-byte units) --------
    int* ws32 = (int*)d_ws;
    double* acc     = (double*)d_ws;
    int* bCurD      = ws32 + 64;
    int* bCurS      = ws32 + 320;
    unsigned* Wp1   = (unsigned*)(ws32 + 1024);
    unsigned* Wp2   = Wp1 + 8192;
    int* rowptrBase = ws32 + 17408;
    float* rsIBase  = (float*)(ws32 + 217412);
    float* rsOBase  = (float*)(ws32 + 417412);
    int* eixBase    = ws32 + 617412;
    int* pairs      = ws32 + 3017412;
    unsigned short* svals = (unsigned short*)(pairs + 4194304);
    unsigned char* xbA    = (unsigned char*)(ws32 + 3017412);

    auto needBytes = [](int gb) -> size_t {
        size_t ov = (size_t)gb * 3200000;   // xb + Ab per graph (fp8), 4B units
        if (ov < 6291456) ov = 6291456;     // at least pairs+svals overlay
        return (3017412 + ov) * 4;
    };
    // ROUND 13 single change: prefer gb=2 (12.8 MB hot set/dispatch vs 25.6 MB)
    int gb = 1;
    if (ws_size >= needBytes(2)) gb = 2;
    else if (ws_size >= needBytes(4)) gb = 4;   // unreachable; kept for safety
    unsigned char* AbA = xbA + (size_t)gb * N_NODES * D;

    const int paGrid    = (N_EDGES + EPB - 1) / EPB;       // 293
    const int xconvGrid = (N_NODES * 16 + 255) / 256;      // 3125

    hipMemsetAsync(d_ws, 0, 1024 * sizeof(int), stream);

    wconv_kernel<<<dim3(32, 2), 256, 0, stream>>>(W1, W2, Wp1, Wp2);
    phaseA_kernel<<<dim3(paGrid, 4), 256, 0, stream>>>(
        src[0], src[1], src[2], src[3], dst[0], dst[1], dst[2], dst[3],
        bCurD, bCurS, pairs, svals, N_EDGES);
    csrB_kernel<<<dim3(NBUCK, 4), 256, 0, stream>>>(
        bCurD, pairs, rowptrBase, eixBase, rsIBase);
    csrC_kernel<<<dim3(NBUCK, 4), 256, 0, stream>>>(bCurS, svals, rsOBase);

    for (int g0 = 0; g0 < 4; g0 += gb) {
        int nb = 4 - g0 < gb ? 4 - g0 : gb;
        xconv_kernel<<<dim3(xconvGrid, nb), 256, 0, stream>>>(
            (const float4*)x[0], (const float4*)x[1], (const float4*)x[2], (const float4*)x[3],
            rsOBase, (uint2*)xbA, g0, N_NODES * 16);
        fused_kernel<1><<<dim3(NCH32, nb), 256, 0, stream>>>(
            rowptrBase, eixBase, xbA, rsIBase, rsOBase,
            (const uint4*)Wp1, b1, AbA, nullptr, g0);
        fused_kernel<2><<<dim3(NCH32, nb), 256, 0, stream>>>(
            rowptrBase, eixBase, AbA, rsIBase, rsOBase,
            (const uint4*)Wp2, b2, nullptr, acc, g0);
    }

    finalize_kernel<<<1, 64, 0, stream>>>(acc, out);
}

// Round 14
// 278.824 us; speedup vs baseline: 1.3064x; 1.0991x over previous
//
#include <hip/hip_runtime.h>
#include <hip/hip_bf16.h>

#define N_NODES 50000
#define N_EDGES 600000
#define D 128

#define NBUCK 64
#define BUCK_R 782      // ceil(N/64); 64*782 = 50048
#define BCAP 16384      // per-bucket capacity (mean 9375, std 96)
#define EPB 2048        // edges per phaseA block

typedef __attribute__((ext_vector_type(8))) short bf16x8;
typedef __attribute__((ext_vector_type(4))) float f32x4;
typedef __attribute__((ext_vector_type(2))) float f32x2;

__device__ __forceinline__ const int* pick4(const int* a, const int* b,
                                            const int* c, const int* d, int g) {
    return g == 0 ? a : g == 1 ? b : g == 2 ? c : d;
}
__device__ __forceinline__ const float4* pick4f(const float4* a, const float4* b,
                                                const float4* c, const float4* d, int g) {
    return g == 0 ? a : g == 1 ? b : g == 2 ? c : d;
}

__device__ __forceinline__ unsigned bfpair(float a, float b) {   // RNE pack: lo=a, hi=b
    unsigned ua = __float_as_uint(a); ua = (ua + 0x7FFF + ((ua >> 16) & 1)) >> 16;
    unsigned ub = __float_as_uint(b); ub = (ub + 0x7FFF + ((ub >> 16) & 1)) >> 16;
    return ua | (ub << 16);
}

// ---------- phase A: bucket edges by dst (pairs) and by src (svals) ----------
__global__ __launch_bounds__(256) void phaseA_kernel(
        const int* s0, const int* s1, const int* s2, const int* s3,
        const int* d0, const int* d1, const int* d2, const int* d3,
        int* __restrict__ bCurD, int* __restrict__ bCurS,
        int* __restrict__ pairs, unsigned short* __restrict__ svals, int nEdges) {
    int gi = blockIdx.y;
    const int* src = pick4(s0, s1, s2, s3, gi);
    const int* dst = pick4(d0, d1, d2, d3, gi);
    int* pg = pairs + (size_t)gi * NBUCK * BCAP;
    unsigned short* sg = svals + (size_t)gi * NBUCK * BCAP;

    __shared__ int cntD[64], cntS[64], gposD[64], gposS[64], lcurD[64], lcurS[64];
    int t = threadIdx.x;
    if (t < 64) { cntD[t] = 0; cntS[t] = 0; }
    __syncthreads();

    int myD[8], myS[8];
    int base = blockIdx.x * EPB + t;
    #pragma unroll
    for (int j = 0; j < 8; ++j) {
        int e = base + j * 256;
        if (e < nEdges) {
            myD[j] = dst[e]; myS[j] = src[e];
            atomicAdd(&cntD[myD[j] / BUCK_R], 1);
            atomicAdd(&cntS[myS[j] / BUCK_R], 1);
        } else myD[j] = -1;
    }
    __syncthreads();
    if (t < 64) {
        int c = cntD[t];
        gposD[t] = t * BCAP + (c ? atomicAdd(&bCurD[gi * 64 + t], c) : 0);
        lcurD[t] = 0;
        c = cntS[t];
        gposS[t] = t * BCAP + (c ? atomicAdd(&bCurS[gi * 64 + t], c) : 0);
        lcurS[t] = 0;
    }
    __syncthreads();
    #pragma unroll
    for (int j = 0; j < 8; ++j) {
        if (myD[j] >= 0) {
            int bD = myD[j] / BUCK_R, bS = myS[j] / BUCK_R;
            int lp = atomicAdd(&lcurD[bD], 1);
            pg[gposD[bD] + lp] = ((myD[j] - bD * BUCK_R) << 16) | myS[j];
            int ls = atomicAdd(&lcurS[bS], 1);
            sg[gposS[bS] + ls] = (unsigned short)(myS[j] - bS * BUCK_R);
        }
    }
}

// ---------- csrB (+merged csrC): per (graph,bucket): LDS hist + scan + scatter
// -> rowptr/rsI/eidx, then src-slice histogram -> rsO ----------
__global__ __launch_bounds__(256) void csrB_kernel(
        const int* __restrict__ bCurD, const int* __restrict__ pairs,
        const int* __restrict__ bCurS, const unsigned short* __restrict__ svals,
        int* __restrict__ rowptrBase, int* __restrict__ eixBase,
        float* __restrict__ rsIBase, float* __restrict__ rsOBase) {
    int gi = blockIdx.y, b = blockIdx.x;
    int* rowptr = rowptrBase + (size_t)gi * (N_NODES + 1);
    int* eidx = eixBase + (size_t)gi * N_EDGES;
    float* rsI = rsIBase + (size_t)gi * N_NODES;
    float* rsO = rsOBase + (size_t)gi * N_NODES;
    const int* pg = pairs + ((size_t)gi * NBUCK + b) * BCAP;
    const unsigned short* sg = svals + ((size_t)gi * NBUCK + b) * BCAP;
    const int* bCur = bCurD + gi * 64;

    __shared__ int P[BCAP];
    __shared__ int cnt[1024];
    __shared__ int cur[1024];
    __shared__ int wpart[4];
    __shared__ int sbase;

    int t = threadIdx.x;
    int nb = bCur[b]; if (nb > BCAP) nb = BCAP;

    if (t < 64) {
        int v = (t < b) ? min(bCur[t], BCAP) : 0;
        for (int off = 32; off; off >>= 1) v += __shfl_down(v, off, 64);
        if (t == 0) sbase = v;
    }
    for (int i = t; i < 1024; i += 256) cnt[i] = 0;
    __syncthreads();
    int base = sbase;

    for (int i = t; i < nb; i += 256) {
        int p = pg[i];
        P[i] = p;
        atomicAdd(&cnt[p >> 16], 1);
    }
    __syncthreads();

    int c0 = cnt[t * 4 + 0], c1 = cnt[t * 4 + 1], c2 = cnt[t * 4 + 2], c3 = cnt[t * 4 + 3];
    int ts = c0 + c1 + c2 + c3;
    int lane = t & 63, w = t >> 6;
    int incl = ts;
    for (int off = 1; off < 64; off <<= 1) {
        int u = __shfl_up(incl, off, 64);
        if (lane >= off) incl += u;
    }
    if (lane == 63) wpart[w] = incl;
    __syncthreads();
    int wb = 0;
    #pragma unroll
    for (int i = 0; i < 4; ++i) if (i < w) wb += wpart[i];
    int ex = wb + incl - ts;
    cur[t * 4 + 0] = ex;
    cur[t * 4 + 1] = ex + c0;
    cur[t * 4 + 2] = ex + c0 + c1;
    cur[t * 4 + 3] = ex + c0 + c1 + c2;
    __syncthreads();

    int lo = b * BUCK_R;
    int nh = N_NODES - lo; if (nh > BUCK_R) nh = BUCK_R;
    for (int i = t; i < nh; i += 256) {
        rowptr[lo + i] = base + cur[i];
        rsI[lo + i] = 1.0f / sqrtf(fmaxf((float)cnt[i], 1.0f));
    }
    if (b == NBUCK - 1 && t == 0) rowptr[N_NODES] = N_EDGES;
    __syncthreads();

    for (int i = t; i < nb; i += 256) {
        int p = P[i];
        int pos = atomicAdd(&cur[p >> 16], 1);
        eidx[base + pos] = p & 0xFFFF;   // src
    }

    // ---- merged csrC: src-slice histogram -> rsO ----
    __syncthreads();                     // cnt reads (rsI) + scatter done
    for (int i = t; i < 1024; i += 256) cnt[i] = 0;
    __syncthreads();
    int ns = bCurS[gi * 64 + b]; if (ns > BCAP) ns = BCAP;
    for (int i = t; i < ns; i += 256) atomicAdd(&cnt[sg[i]], 1);
    __syncthreads();
    for (int i = t; i < nh; i += 256)
        rsO[lo + i] = 1.0f / sqrtf(fmaxf((float)cnt[i], 1.0f));
}

// ---------- W fp32 -> packed bf16 MFMA B-fragment layout ----------
__global__ void wconv_kernel(const float* __restrict__ W1, const float* __restrict__ W2,
                             unsigned* __restrict__ Wp1, unsigned* __restrict__ Wp2) {
    const float* W = blockIdx.y ? W2 : W1;
    unsigned* Wp = blockIdx.y ? Wp2 : Wp1;
    int o = blockIdx.x * 256 + threadIdx.x;      // 0..8191
    int j2 = o & 3, lane = (o >> 2) & 63, nt = (o >> 8) & 7, kc = o >> 11;
    int k = kc * 32 + (lane >> 4) * 8 + j2 * 2;
    int col = nt * 16 + (lane & 15);
    Wp[o] = bfpair(W[k * 128 + col], W[(k + 1) * 128 + col]);
}

// ---------- x -> fp8 e4m3 with rsO pre-scale, row-major [N][128] ----------
__global__ void xconv_kernel(const float4* x0, const float4* x1,
                             const float4* x2, const float4* x3,
                             const float* __restrict__ rsOBase,
                             uint2* __restrict__ xbBase, int gFirst, int n /* N*16 */) {
    int gi = blockIdx.y;
    const float4* x = pick4f(x0, x1, x2, x3, gFirst + gi);
    const float* rsO = rsOBase + (size_t)(gFirst + gi) * N_NODES;
    uint2* xb = xbBase + (size_t)gi * (N_NODES * 16);   // 16 uint2 per 128-fp8 row
    int i = blockIdx.x * blockDim.x + threadIdx.x;
    if (i >= n) return;
    float sc = rsO[i >> 4];
    float4 a = x[i * 2];
    float4 b = x[i * 2 + 1];
    int w0 = __builtin_amdgcn_cvt_pk_fp8_f32(a.x * sc, a.y * sc, 0, false);
    w0 = __builtin_amdgcn_cvt_pk_fp8_f32(a.z * sc, a.w * sc, w0, true);
    int w1 = __builtin_amdgcn_cvt_pk_fp8_f32(b.x * sc, b.y * sc, 0, false);
    w1 = __builtin_amdgcn_cvt_pk_fp8_f32(b.z * sc, b.w * sc, w1, true);
    xb[i] = make_uint2((unsigned)w0, (unsigned)w1);
}

// ---------- fused gather (fp8, 16B loads, unroll-4) + MFMA GEMM (bf16 W) ----------
// 32-row chunk per block: 8 thr/row gather h[eidx[p]] via uint4 (16 fp8), 4 edges
// in flight; f32 accum; rsI-scale; bf16 -> LDS A[32][136]; 4 waves do 2 row-tiles
// x 2 col-tiles of 16x16x32 MFMA.
// LAYER 1: out fp8 = fp8(relu(.+b)*rsO);  LAYER 2: acc += sum(relu(.+b))
#define NCH32 1563   // ceil(50000/32)

#define ACC16(U)                                                            \
    {                                                                       \
        f32x2 e0 = __builtin_amdgcn_cvt_pk_f32_fp8((U).x, false);           \
        f32x2 e1 = __builtin_amdgcn_cvt_pk_f32_fp8((U).x, true);            \
        f32x2 e2 = __builtin_amdgcn_cvt_pk_f32_fp8((U).y, false);           \
        f32x2 e3 = __builtin_amdgcn_cvt_pk_f32_fp8((U).y, true);            \
        f32x2 e4 = __builtin_amdgcn_cvt_pk_f32_fp8((U).z, false);           \
        f32x2 e5 = __builtin_amdgcn_cvt_pk_f32_fp8((U).z, true);            \
        f32x2 e6 = __builtin_amdgcn_cvt_pk_f32_fp8((U).w, false);           \
        f32x2 e7 = __builtin_amdgcn_cvt_pk_f32_fp8((U).w, true);            \
        a[0] += e0[0];  a[1] += e0[1];  a[2] += e1[0];  a[3] += e1[1];      \
        a[4] += e2[0];  a[5] += e2[1];  a[6] += e3[0];  a[7] += e3[1];      \
        a[8] += e4[0];  a[9] += e4[1];  a[10] += e5[0]; a[11] += e5[1];     \
        a[12] += e6[0]; a[13] += e6[1]; a[14] += e7[0]; a[15] += e7[1];     \
    }

template <int LAYER>
__global__ __launch_bounds__(256) void fused_kernel(
        const int* __restrict__ rowptrBase, const int* __restrict__ eixBase,
        const unsigned char* __restrict__ hBase,     // [gli][N][128] fp8
        const float* __restrict__ rsIBase, const float* __restrict__ rsOBase,
        const uint4* __restrict__ Wp, const float* __restrict__ bias,
        unsigned char* __restrict__ outBase, double* __restrict__ acc, int gFirst) {
    const int gi = blockIdx.y;
    const int g = gFirst + gi;
    const int* rowptr = rowptrBase + (size_t)g * (N_NODES + 1);
    const int* eidx   = eixBase + (size_t)g * N_EDGES;
    const float* rsI  = rsIBase + (size_t)g * N_NODES;
    const float* rsO  = rsOBase + (size_t)g * N_NODES;
    const unsigned char* h = hBase + (size_t)gi * N_NODES * D;
    unsigned char* outb = outBase + (size_t)gi * N_NODES * D;

    __shared__ unsigned short A[32][136];    // bf16 staging, padded stride

    const int t = threadIdx.x;
    const int row = t >> 3;          // 0..31
    const int sub = t & 7;           // 16-col (16 B) slice
    const int lane = t & 63, wv = t >> 6;
    const int l15 = lane & 15, lh = lane >> 4;

    // W fragments: register-resident
    bf16x8 bfr[4][2];
    #pragma unroll
    for (int kc = 0; kc < 4; ++kc)
        #pragma unroll
        for (int j = 0; j < 2; ++j) {
            uint4 u = Wp[(kc * 8 + wv * 2 + j) * 64 + lane];
            bfr[kc][j] = *(bf16x8*)&u;
        }
    float bv[2];
    #pragma unroll
    for (int j = 0; j < 2; ++j) bv[j] = bias[wv * 32 + j * 16 + l15];

    const int ch = blockIdx.x;
    const int r = ch * 32 + row;
    int p = 0, pend = 0;
    float sc = 0.f;
    if (r < N_NODES) { p = rowptr[r]; pend = rowptr[r + 1]; sc = rsI[r]; }

    // ---- gather phase: 16 B/edge/thread, 4 edges in flight ----
    float a[16];
    #pragma unroll
    for (int j = 0; j < 16; ++j) a[j] = 0.f;
    const unsigned char* hp = h + sub * 16;
    for (; p + 4 <= pend; p += 4) {
        uint4 u0 = *(const uint4*)(hp + (size_t)eidx[p] * 128);
        uint4 u1 = *(const uint4*)(hp + (size_t)eidx[p + 1] * 128);
        uint4 u2 = *(const uint4*)(hp + (size_t)eidx[p + 2] * 128);
        uint4 u3 = *(const uint4*)(hp + (size_t)eidx[p + 3] * 128);
        ACC16(u0) ACC16(u1) ACC16(u2) ACC16(u3)
    }
    for (; p < pend; ++p) {
        uint4 u0 = *(const uint4*)(hp + (size_t)eidx[p] * 128);
        ACC16(u0)
    }
    {
        uint4 pkA, pkB;
        pkA.x = bfpair(a[0] * sc, a[1] * sc);
        pkA.y = bfpair(a[2] * sc, a[3] * sc);
        pkA.z = bfpair(a[4] * sc, a[5] * sc);
        pkA.w = bfpair(a[6] * sc, a[7] * sc);
        pkB.x = bfpair(a[8] * sc, a[9] * sc);
        pkB.y = bfpair(a[10] * sc, a[11] * sc);
        pkB.z = bfpair(a[12] * sc, a[13] * sc);
        pkB.w = bfpair(a[14] * sc, a[15] * sc);
        *(uint4*)&A[row][sub * 16]     = pkA;
        *(uint4*)&A[row][sub * 16 + 8] = pkB;
    }
    __syncthreads();

    // ---- MFMA phase: 2 row-tiles x 2 col-tiles ----
    f32x4 c[2][2];
    #pragma unroll
    for (int ti = 0; ti < 2; ++ti) {
        c[ti][0] = (f32x4){0.f, 0.f, 0.f, 0.f};
        c[ti][1] = (f32x4){0.f, 0.f, 0.f, 0.f};
    }
    #pragma unroll
    for (int ti = 0; ti < 2; ++ti) {
        #pragma unroll
        for (int kc = 0; kc < 4; ++kc) {
            uint4 u = *(const uint4*)&A[ti * 16 + l15][kc * 32 + lh * 8];
            bf16x8 afr = *(bf16x8*)&u;
            c[ti][0] = __builtin_amdgcn_mfma_f32_16x16x32_bf16(afr, bfr[kc][0], c[ti][0], 0, 0, 0);
            c[ti][1] = __builtin_amdgcn_mfma_f32_16x16x32_bf16(afr, bfr[kc][1], c[ti][1], 0, 0, 0);
        }
    }

    // ---- epilogue ----
    double lsum = 0.0;
    #pragma unroll
    for (int ti = 0; ti < 2; ++ti) {
        const int r0 = ch * 32 + ti * 16 + lh * 4;
        #pragma unroll
        for (int jj = 0; jj < 4; ++jj) {
            int rr = r0 + jj;
            if (rr < N_NODES) {
                float o0 = fmaxf(c[ti][0][jj] + bv[0], 0.f);
                float o1 = fmaxf(c[ti][1][jj] + bv[1], 0.f);
                if (LAYER == 2) {
                    lsum += (double)o0 + (double)o1;
                } else {
                    float s2 = rsO[rr];
                    float q0 = o0 * s2, q1 = o1 * s2;
                    unsigned b0 = (unsigned)__builtin_amdgcn_cvt_pk_fp8_f32(q0, q0, 0, false);
                    unsigned b1 = (unsigned)__builtin_amdgcn_cvt_pk_fp8_f32(q1, q1, 0, false);
                    outb[(size_t)rr * 128 + wv * 32 + l15]      = (unsigned char)(b0 & 0xFF);
                    outb[(size_t)rr * 128 + wv * 32 + 16 + l15] = (unsigned char)(b1 & 0xFF);
                }
            }
        }
    }

    if (LAYER == 2) {
        for (int off = 32; off; off >>= 1) lsum += __shfl_down(lsum, off, 64);
        __shared__ double wred[4];
        if (lane == 0) wred[wv] = lsum;
        __syncthreads();
        if (t == 0) atomicAdd(acc, wred[0] + wred[1] + wred[2] + wred[3]);
    }
}

__global__ void finalize_kernel(const double* __restrict__ acc, float* __restrict__ out) {
    if (threadIdx.x == 0 && blockIdx.x == 0)
        out[0] = (float)(acc[0] / (4.0 * N_NODES * D));
}

extern "C" void kernel_launch(void* const* d_in, const int* in_sizes, int n_in,
                              void* d_out, int out_size, void* d_ws, size_t ws_size,
                              hipStream_t stream) {
    const float* x[4];
    const int* src[4];
    const int* dst[4];
    for (int g = 0; g < 4; ++g) {
        x[g]   = (const float*)d_in[3 * g + 0];
        src[g] = (const int*)  d_in[3 * g + 1];
        dst[g] = (const int*)  d_in[3 * g + 2];
    }
    const float* W1 = (const float*)d_in[12];
    const float* b1 = (const float*)d_in[13];
    const float* W2 = (const float*)d_in[14];
    const float* b2 = (const float*)d_in[15];
    float* out = (float*)d_out;

    // -------- workspace layout (4-byte units) --------
    int* ws32 = (int*)d_ws;
    double* acc     = (double*)d_ws;
    int* bCurD      = ws32 + 64;
    int* bCurS      = ws32 + 320;
    unsigned* Wp1   = (unsigned*)(ws32 + 1024);
    unsigned* Wp2   = Wp1 + 8192;
    int* rowptrBase = ws32 + 17408;
    float* rsIBase  = (float*)(ws32 + 217412);
    float* rsOBase  = (float*)(ws32 + 417412);
    int* eixBase    = ws32 + 617412;
    int* pairs      = ws32 + 3017412;
    unsigned short* svals = (unsigned short*)(pairs + 4194304);
    unsigned char* xbA    = (unsigned char*)(ws32 + 3017412);

    auto needBytes = [](int gb) -> size_t {
        size_t ov = (size_t)gb * 3200000;   // xb + Ab per graph (fp8), 4B units
        if (ov < 6291456) ov = 6291456;     // at least pairs+svals overlay
        return (3017412 + ov) * 4;
    };
    // ROUND 14: revert to gb=4 (round-11 proven optimum; round-13 gb=2 regressed)
    int gb = 1;
    if (ws_size >= needBytes(4)) gb = 4;
    else if (ws_size >= needBytes(2)) gb = 2;
    unsigned char* AbA = xbA + (size_t)gb * N_NODES * D;

    const int paGrid    = (N_EDGES + EPB - 1) / EPB;       // 293
    const int xconvGrid = (N_NODES * 16 + 255) / 256;      // 3125

    hipMemsetAsync(d_ws, 0, 1024 * sizeof(int), stream);

    wconv_kernel<<<dim3(32, 2), 256, 0, stream>>>(W1, W2, Wp1, Wp2);
    phaseA_kernel<<<dim3(paGrid, 4), 256, 0, stream>>>(
        src[0], src[1], src[2], src[3], dst[0], dst[1], dst[2], dst[3],
        bCurD, bCurS, pairs, svals, N_EDGES);
    csrB_kernel<<<dim3(NBUCK, 4), 256, 0, stream>>>(
        bCurD, pairs, bCurS, svals, rowptrBase, eixBase, rsIBase, rsOBase);

    for (int g0 = 0; g0 < 4; g0 += gb) {
        int nb = 4 - g0 < gb ? 4 - g0 : gb;
        xconv_kernel<<<dim3(xconvGrid, nb), 256, 0, stream>>>(
            (const float4*)x[0], (const float4*)x[1], (const float4*)x[2], (const float4*)x[3],
            rsOBase, (uint2*)xbA, g0, N_NODES * 16);
        fused_kernel<1><<<dim3(NCH32, nb), 256, 0, stream>>>(
            rowptrBase, eixBase, xbA, rsIBase, rsOBase,
            (const uint4*)Wp1, b1, AbA, nullptr, g0);
        fused_kernel<2><<<dim3(NCH32, nb), 256, 0, stream>>>(
            rowptrBase, eixBase, AbA, rsIBase, rsOBase,
            (const uint4*)Wp2, b2, nullptr, acc, g0);
    }

    finalize_kernel<<<1, 64, 0, stream>>>(acc, out);
}